// Round 1
// baseline (181.496 us; speedup 1.0000x reference)
//
#include <hip/hip_runtime.h>

#define H 1024
#define W 1024
#define NPIX (H * W)
#define NIMG 12
#define TOT (NIMG * NPIX)

// Constants computed in double then demoted to float, matching Python/JAX
// weak-typed scalar demotion.
__device__ __constant__ float C_HALF = (float)(0.5 * (1.0 / 1023.0));
__device__ __constant__ float C_FOUR = (float)(4.0 * (1.0 / 1023.0));
__device__ __constant__ float C_ONE  = (float)(1.0 * (1.0 / 1023.0));
#define SCALE 255.75f  /* 1023/4, exact */

// ---------------------------------------------------------------- gm kernel
__global__ __launch_bounds__(256) void gm_kernel(const float* __restrict__ in,
                                                 float* __restrict__ gm) {
    int idx = blockIdx.x * blockDim.x + threadIdx.x;
    if (idx >= TOT) return;
    int img = idx >> 20;
    int p   = idx & (NPIX - 1);
    int y = p >> 10, x = p & 1023;
    const float* im = in + (size_t)img * NPIX;

    // axis = 1 (x): d(k) = im[y][x-k] - im[y][x+k], zero fill
    float xm1 = (x >= 1)     ? im[p - 1] : 0.0f;
    float xp1 = (x < W - 1)  ? im[p + 1] : 0.0f;
    float xm2 = (x >= 2)     ? im[p - 2] : 0.0f;
    float xp2 = (x < W - 2)  ? im[p + 2] : 0.0f;
    float xm3 = (x >= 3)     ? im[p - 3] : 0.0f;
    float xp3 = (x < W - 3)  ? im[p + 3] : 0.0f;
    float g1 = xm1 - xp1;
    float g2 = xm2 - xp2;
    float g3 = xm3 - xp3;
    float gmer = (g1 + g2 + g3) / 3.0f;
    float a = fabsf(g1);
    bool keep = (fabsf(gmer - g1) <= C_HALF) & (a <= C_FOUR) & (a > C_ONE);
    float gx = keep ? a : 0.0f;

    // axis = 0 (y): d(k) = im[y-k][x] - im[y+k][x], zero fill
    float ym1 = (y >= 1)    ? im[p - W]     : 0.0f;
    float yp1 = (y < H - 1) ? im[p + W]     : 0.0f;
    float ym2 = (y >= 2)    ? im[p - 2 * W] : 0.0f;
    float yp2 = (y < H - 2) ? im[p + 2 * W] : 0.0f;
    float ym3 = (y >= 3)    ? im[p - 3 * W] : 0.0f;
    float yp3 = (y < H - 3) ? im[p + 3 * W] : 0.0f;
    g1 = ym1 - yp1;
    g2 = ym2 - yp2;
    g3 = ym3 - yp3;
    gmer = (g1 + g2 + g3) / 3.0f;
    a = fabsf(g1);
    keep = (fabsf(gmer - g1) <= C_HALF) & (a <= C_FOUR) & (a > C_ONE);
    float gy = keep ? a : 0.0f;

    gm[idx] = fmaxf(gx, gy) * SCALE;
}

// ------------------------------------------------------------- init labels
__global__ __launch_bounds__(256) void init_labels(const float* __restrict__ gm,
                                                   int* __restrict__ labels) {
    int idx = blockIdx.x * blockDim.x + threadIdx.x;
    if (idx >= TOT) return;
    labels[idx] = (gm[idx] > 1.0f) ? (idx & (NPIX - 1)) : NPIX;
}

// ------------------------------------------------------------- union-find
__device__ __forceinline__ int find_root(int* L, int a) {
    int l = L[a];
    while (l != a) { a = l; l = L[a]; }
    return a;
}

__device__ __forceinline__ void unite(int* L, int a, int b) {
    while (true) {
        a = find_root(L, a);
        b = find_root(L, b);
        if (a == b) return;
        if (a > b) { int t = a; a = b; b = t; }
        int old = atomicMin(&L[b], a);
        if (old == b) return;
        b = old;
    }
}

__global__ __launch_bounds__(256) void merge_kernel(const float* __restrict__ gm,
                                                    int* __restrict__ labels) {
    int idx = blockIdx.x * blockDim.x + threadIdx.x;
    if (idx >= TOT) return;
    int img = idx >> 20;
    int p   = idx & (NPIX - 1);
    const float* g = gm + (size_t)img * NPIX;
    if (!(g[p] > 1.0f)) return;
    int y = p >> 10, x = p & 1023;
    int* L = labels + (size_t)img * NPIX;
    // forward 8-neighbors: E, SW, S, SE (each edge handled once)
    if (x < W - 1 && g[p + 1] > 1.0f) unite(L, p, p + 1);
    if (y < H - 1) {
        if (x >= 1    && g[p + W - 1] > 1.0f) unite(L, p, p + W - 1);
        if (              g[p + W]     > 1.0f) unite(L, p, p + W);
        if (x < W - 1 && g[p + W + 1] > 1.0f) unite(L, p, p + W + 1);
    }
}

__global__ __launch_bounds__(256) void flatten_kernel(const float* __restrict__ gm,
                                                      int* __restrict__ labels) {
    int idx = blockIdx.x * blockDim.x + threadIdx.x;
    if (idx >= TOT) return;
    int img = idx >> 20;
    int p   = idx & (NPIX - 1);
    if (!(gm[idx] > 1.0f)) return;
    int* L = labels + (size_t)img * NPIX;
    L[p] = find_root(L, p);
}

// ----------------------------------------------------------- boundary count
__global__ __launch_bounds__(256) void count_kernel(const float* __restrict__ gm,
                                                    const int* __restrict__ labels,
                                                    int* __restrict__ counts) {
    int idx = blockIdx.x * blockDim.x + threadIdx.x;
    if (idx >= TOT) return;
    int img = idx >> 20;
    int p   = idx & (NPIX - 1);
    const float* g = gm + (size_t)img * NPIX;
    if (!(g[p] > 1.0f)) return;
    int y = p >> 10, x = p & 1023;
    bool interior = (y >= 1 && g[p - W] > 1.0f) && (y < H - 1 && g[p + W] > 1.0f) &&
                    (x >= 1 && g[p - 1] > 1.0f) && (x < W - 1 && g[p + 1] > 1.0f);
    if (!interior) {
        atomicAdd(&counts[(size_t)img * NPIX + labels[idx]], 1);
    }
}

// ---------------------------------------------------------------- final
__device__ __forceinline__ float gm_at(const float* g, int y, int x) {
    // zero fill outside
    if (y < 0 || y >= H || x < 0 || x >= W) return 0.0f;
    return g[y * W + x];
}

__global__ __launch_bounds__(256) void final_kernel(const float* __restrict__ gm,
                                                    const int* __restrict__ labels,
                                                    const int* __restrict__ counts,
                                                    float* __restrict__ out) {
    int idx = blockIdx.x * blockDim.x + threadIdx.x;
    if (idx >= TOT) return;
    int img = idx >> 20;
    int p   = idx & (NPIX - 1);
    int y = p >> 10, x = p & 1023;
    const float* g = gm + (size_t)img * NPIX;

    // directmask: 3x3 reflect blur of gradient products; grads use zero fill
    float sxx = 0.0f, syy = 0.0f, sxy = 0.0f;
    #pragma unroll
    for (int di = -1; di <= 1; ++di) {
        int r = y + di;
        if (r < 0) r = -r;              // reflect: -1 -> 1
        if (r >= H) r = 2 * H - 2 - r;  // reflect: H -> H-2
        #pragma unroll
        for (int dj = -1; dj <= 1; ++dj) {
            int c = x + dj;
            if (c < 0) c = -c;
            if (c >= W) c = 2 * W - 2 - c;
            float gxv = gm_at(g, r, c - 1) - gm_at(g, r, c + 1);
            float gyv = gm_at(g, r - 1, c) - gm_at(g, r + 1, c);
            sxx += gxv * gxv;
            syy += gyv * gyv;
            sxy += gxv * gyv;
        }
    }
    sxx /= 9.0f; syy /= 9.0f; sxy /= 9.0f;
    float d = sxx - syy;
    float tmp = sqrtf(d * d + 4.0f * sxy * sxy);
    float dm = tmp / (sxx + syy + 1e-16f);

    // lengthmask value
    float gc = g[p];
    float lm = 0.0f;
    if (gc > 1.0f) {
        bool interior = (y >= 1 && g[p - W] > 1.0f) && (y < H - 1 && g[p + W] > 1.0f) &&
                        (x >= 1 && g[p - 1] > 1.0f) && (x < W - 1 && g[p + 1] > 1.0f);
        if (!interior) {
            int c = counts[(size_t)img * NPIX + labels[idx]];
            float cf = (float)c;
            if (cf > 21.0f) lm = cf;
        }
    }

    float v = gc * dm * lm;
    v = fminf(fmaxf(v, 0.0f), 1.0f);
    out[idx] = v;
}

// ---------------------------------------------------------------- launch
extern "C" void kernel_launch(void* const* d_in, const int* in_sizes, int n_in,
                              void* d_out, int out_size, void* d_ws, size_t ws_size,
                              hipStream_t stream) {
    const float* base = (const float*)d_in[0];
    float* out = (float*)d_out;

    float* gm     = (float*)d_ws;
    int*   labels = (int*)((char*)d_ws + (size_t)TOT * 4);
    int*   counts = (int*)((char*)d_ws + 2ull * (size_t)TOT * 4);

    dim3 block(256);
    dim3 grid((TOT + 255) / 256);

    hipMemsetAsync(counts, 0, (size_t)TOT * 4, stream);
    gm_kernel<<<grid, block, 0, stream>>>(base, gm);
    init_labels<<<grid, block, 0, stream>>>(gm, labels);
    merge_kernel<<<grid, block, 0, stream>>>(gm, labels);
    flatten_kernel<<<grid, block, 0, stream>>>(gm, labels);
    count_kernel<<<grid, block, 0, stream>>>(gm, labels, counts);
    final_kernel<<<grid, block, 0, stream>>>(gm, labels, counts, out);
}

// Round 2
// 100.222 us; speedup vs baseline: 1.8109x; 1.8109x over previous
//
#include <hip/hip_runtime.h>

#define H 1024
#define W 1024
#define NPIX (H * W)
#define NIMG 12
#define TOT (NIMG * NPIX)
#define NWORDS (TOT / 64)   /* 196608 fg-mask words (64 px each) */
#define WPR 16              /* mask words per image row */
#define WPI (NPIX / 64)     /* mask words per image */

typedef unsigned long long ull;

// Constants computed in double then demoted to float, matching Python/JAX.
__device__ __constant__ float C_HALF = (float)(0.5 * (1.0 / 1023.0));
__device__ __constant__ float C_FOUR = (float)(4.0 * (1.0 / 1023.0));
__device__ __constant__ float C_ONE  = (float)(1.0 * (1.0 / 1023.0));
#define SCALE 255.75f  /* 1023/4, exact */

// ------------------------------------------------------------------ gm pass
// Computes gm, emits fg bitmask (if mask != nullptr), and initializes
// labels/counts ONLY at fg pixels (non-fg entries are never read downstream).
__global__ __launch_bounds__(256) void gm_kernel(const float* __restrict__ in,
                                                 float* __restrict__ gm,
                                                 ull* __restrict__ mask,
                                                 int* __restrict__ labels,
                                                 int* __restrict__ counts) {
    int idx = blockIdx.x * blockDim.x + threadIdx.x;
    int p   = idx & (NPIX - 1);
    int y = p >> 10, x = p & 1023;
    const float* im = in + ((size_t)(idx >> 20) << 20);

    float xm1 = (x >= 1)     ? im[p - 1] : 0.0f;
    float xp1 = (x < W - 1)  ? im[p + 1] : 0.0f;
    float xm2 = (x >= 2)     ? im[p - 2] : 0.0f;
    float xp2 = (x < W - 2)  ? im[p + 2] : 0.0f;
    float xm3 = (x >= 3)     ? im[p - 3] : 0.0f;
    float xp3 = (x < W - 3)  ? im[p + 3] : 0.0f;
    float g1 = xm1 - xp1;
    float g2 = xm2 - xp2;
    float g3 = xm3 - xp3;
    float gmer = (g1 + g2 + g3) / 3.0f;
    float a = fabsf(g1);
    bool keep = (fabsf(gmer - g1) <= C_HALF) & (a <= C_FOUR) & (a > C_ONE);
    float gx = keep ? a : 0.0f;

    float ym1 = (y >= 1)    ? im[p - W]     : 0.0f;
    float yp1 = (y < H - 1) ? im[p + W]     : 0.0f;
    float ym2 = (y >= 2)    ? im[p - 2 * W] : 0.0f;
    float yp2 = (y < H - 2) ? im[p + 2 * W] : 0.0f;
    float ym3 = (y >= 3)    ? im[p - 3 * W] : 0.0f;
    float yp3 = (y < H - 3) ? im[p + 3 * W] : 0.0f;
    g1 = ym1 - yp1;
    g2 = ym2 - yp2;
    g3 = ym3 - yp3;
    gmer = (g1 + g2 + g3) / 3.0f;
    a = fabsf(g1);
    keep = (fabsf(gmer - g1) <= C_HALF) & (a <= C_FOUR) & (a > C_ONE);
    float gy = keep ? a : 0.0f;

    float gmv = fmaxf(gx, gy) * SCALE;
    gm[idx] = gmv;

    bool fg = gmv > 1.0f;
    if (mask) {
        ull m = __ballot(fg);
        if ((threadIdx.x & 63) == 0) mask[idx >> 6] = m;
    }
    if (fg) {
        labels[idx] = p;   // per-image pixel index
        counts[idx] = 0;   // roots are fg pixels; zero before count pass
    }
}

// ------------------------------------------------------------- union-find
__device__ __forceinline__ int find_root(int* L, int a) {
    int l = L[a];
    while (l != a) { a = l; l = L[a]; }
    return a;
}

__device__ __forceinline__ void unite(int* L, int a, int b) {
    while (true) {
        a = find_root(L, a);
        b = find_root(L, b);
        if (a == b) return;
        if (a > b) { int t = a; a = b; b = t; }
        int old = atomicMin(&L[b], a);
        if (old == b) return;
        b = old;
    }
}

// ------------------------------------------- word-based (sparse) CCL kernels
__global__ __launch_bounds__(256) void merge_words(const ull* __restrict__ mask,
                                                   int* __restrict__ labels) {
    int w = blockIdx.x * blockDim.x + threadIdx.x;
    ull m = mask[w];
    if (!m) return;
    int img = w >> 14;
    int wp  = w & (WPI - 1);
    int row = wp >> 4, colw = wp & 15;
    int* L = labels + ((size_t)img << 20);
    bool hasS = row < H - 1, hasE = colw < 15, hasW = colw > 0;
    ull mS   = hasS ? mask[w + WPR] : 0ull;
    ull mE1  = hasE ? mask[w + 1] : 0ull;
    ull mSWw = (hasS && hasW) ? mask[w + WPR - 1] : 0ull;
    ull mSEw = (hasS && hasE) ? mask[w + WPR + 1] : 0ull;
    ull fgE  = (m >> 1) | (mE1 << 63);
    ull fgS  = mS;
    ull fgSW = (mS << 1) | (mSWw >> 63);
    ull fgSE = (mS >> 1) | (mSEw << 63);
    int pbase = wp << 6;
    ull t = m;
    while (t) {
        int b = __builtin_ctzll(t);
        t &= t - 1;
        int p = pbase + b;
        ull bit = 1ull << b;
        if (fgE & bit)  unite(L, p, p + 1);
        if (fgSW & bit) unite(L, p, p + W - 1);
        if (fgS & bit)  unite(L, p, p + W);
        if (fgSE & bit) unite(L, p, p + W + 1);
    }
}

__global__ __launch_bounds__(256) void count_words(const ull* __restrict__ mask,
                                                   int* __restrict__ labels,
                                                   int* __restrict__ counts) {
    int w = blockIdx.x * blockDim.x + threadIdx.x;
    ull m = mask[w];
    if (!m) return;
    int img = w >> 14;
    int wp  = w & (WPI - 1);
    int row = wp >> 4, colw = wp & 15;
    int* L = labels + ((size_t)img << 20);
    int* C = counts + ((size_t)img << 20);
    ull mN  = (row > 0)     ? mask[w - WPR] : 0ull;
    ull mS  = (row < H - 1) ? mask[w + WPR] : 0ull;
    ull mE1 = (colw < 15)   ? mask[w + 1]   : 0ull;
    ull mWw = (colw > 0)    ? mask[w - 1]   : 0ull;
    ull fgE = (m >> 1) | (mE1 << 63);
    ull fgW = (m << 1) | (mWw >> 63);
    ull boundary = m & ~(mN & mS & fgE & fgW);
    int pbase = wp << 6;
    while (boundary) {
        int b = __builtin_ctzll(boundary);
        boundary &= boundary - 1;
        int p = pbase + b;
        int r = find_root(L, p);
        L[p] = r;                 // flatten boundary pixels (read by final)
        atomicAdd(&C[r], 1);
    }
}

// ------------------------------------- per-pixel fallback CCL (ws too small)
__global__ __launch_bounds__(256) void merge_px(const float* __restrict__ gm,
                                                int* __restrict__ labels) {
    int idx = blockIdx.x * blockDim.x + threadIdx.x;
    int p = idx & (NPIX - 1);
    const float* g = gm + ((size_t)(idx >> 20) << 20);
    if (!(g[p] > 1.0f)) return;
    int y = p >> 10, x = p & 1023;
    int* L = labels + ((size_t)(idx >> 20) << 20);
    if (x < W - 1 && g[p + 1] > 1.0f) unite(L, p, p + 1);
    if (y < H - 1) {
        if (x >= 1    && g[p + W - 1] > 1.0f) unite(L, p, p + W - 1);
        if (             g[p + W]     > 1.0f) unite(L, p, p + W);
        if (x < W - 1 && g[p + W + 1] > 1.0f) unite(L, p, p + W + 1);
    }
}

__global__ __launch_bounds__(256) void count_px(const float* __restrict__ gm,
                                                int* __restrict__ labels,
                                                int* __restrict__ counts) {
    int idx = blockIdx.x * blockDim.x + threadIdx.x;
    int p = idx & (NPIX - 1);
    const float* g = gm + ((size_t)(idx >> 20) << 20);
    if (!(g[p] > 1.0f)) return;
    int y = p >> 10, x = p & 1023;
    bool interior = (y >= 1 && g[p - W] > 1.0f) && (y < H - 1 && g[p + W] > 1.0f) &&
                    (x >= 1 && g[p - 1] > 1.0f) && (x < W - 1 && g[p + 1] > 1.0f);
    if (!interior) {
        int* L = labels + ((size_t)(idx >> 20) << 20);
        int r = find_root(L, p);
        L[p] = r;
        atomicAdd(&counts[((size_t)(idx >> 20) << 20) + r], 1);
    }
}

// ---------------------------------------------------------------- final
#define TX 64
#define TY 16
#define GW (TX + 4)  /* 68 */
#define PW (TX + 2)  /* 66 */

__global__ __launch_bounds__(256) void final_kernel(const float* __restrict__ gm,
                                                    const int* __restrict__ labels,
                                                    const int* __restrict__ counts,
                                                    float* __restrict__ out) {
    __shared__ float gs[(TY + 4) * GW];
    __shared__ float pxx[(TY + 2) * PW];
    __shared__ float pyy[(TY + 2) * PW];
    __shared__ float pxy[(TY + 2) * PW];

    int bid = blockIdx.x;
    int img = bid >> 10;          // 1024 tiles per image (16 x * 64 y)
    int rem = bid & 1023;
    int ty0 = (rem >> 4) * TY;
    int tx0 = (rem & 15) * TX;
    const float* g = gm + ((size_t)img << 20);
    int t = threadIdx.x;

    // stage gm tile + halo 2 (zero-filled outside image)
    for (int i = t; i < (TY + 4) * GW; i += 256) {
        int ly = i / GW, lx = i - ly * GW;
        int gr = ty0 - 2 + ly, gc = tx0 - 2 + lx;
        float v = 0.0f;
        if ((unsigned)gr < H && (unsigned)gc < W) v = g[gr * W + gc];
        gs[i] = v;
    }
    __syncthreads();

    // gradient products once per (tile + blur-halo-1) pixel
    for (int i = t; i < (TY + 2) * PW; i += 256) {
        int ly = i / PW, lx = i - ly * PW;
        int r = ty0 - 1 + ly, c = tx0 - 1 + lx;
        if ((unsigned)r < H && (unsigned)c < W) {
            float gxv = gs[(ly + 1) * GW + lx]     - gs[(ly + 1) * GW + lx + 2];
            float gyv = gs[ly * GW + lx + 1]       - gs[(ly + 2) * GW + lx + 1];
            pxx[i] = gxv * gxv;
            pyy[i] = gyv * gyv;
            pxy[i] = gxv * gyv;
        }
    }
    __syncthreads();

    int ox = t & 63;
    int x = tx0 + ox;
    // reflected column offsets (fixed per thread)
    int cc[3];
    #pragma unroll
    for (int dj = -1; dj <= 1; ++dj) {
        int cg = x + dj;
        if (cg < 0) cg = -cg;
        if (cg >= W) cg = 2 * W - 2 - cg;
        cc[dj + 1] = cg - tx0 + 1;
    }

    #pragma unroll
    for (int i = 0; i < 4; ++i) {
        int oy = (t >> 6) * 4 + i;
        int y = ty0 + oy;
        int rr[3];
        #pragma unroll
        for (int di = -1; di <= 1; ++di) {
            int rg = y + di;
            if (rg < 0) rg = -rg;
            if (rg >= H) rg = 2 * H - 2 - rg;
            rr[di + 1] = rg - ty0 + 1;
        }
        float sxx = 0.0f, syy = 0.0f, sxy = 0.0f;
        #pragma unroll
        for (int ii = 0; ii < 3; ++ii) {
            int ro = rr[ii] * PW;
            #pragma unroll
            for (int jj = 0; jj < 3; ++jj) {
                int o = ro + cc[jj];
                sxx += pxx[o];
                syy += pyy[o];
                sxy += pxy[o];
            }
        }
        sxx /= 9.0f; syy /= 9.0f; sxy /= 9.0f;
        float d = sxx - syy;
        float tmp = sqrtf(d * d + 4.0f * sxy * sxy);
        float dmv = tmp / (sxx + syy + 1e-16f);

        float gc_ = gs[(oy + 2) * GW + ox + 2];
        float lm = 0.0f;
        if (gc_ > 1.0f) {
            bool interior = (gs[(oy + 1) * GW + ox + 2] > 1.0f) &
                            (gs[(oy + 3) * GW + ox + 2] > 1.0f) &
                            (gs[(oy + 2) * GW + ox + 1] > 1.0f) &
                            (gs[(oy + 2) * GW + ox + 3] > 1.0f);
            if (!interior) {
                int p = y * W + x;
                int c = counts[((size_t)img << 20) + labels[((size_t)img << 20) + p]];
                if (c > 21) lm = (float)c;
            }
        }
        float v = gc_ * dmv * lm;
        v = fminf(fmaxf(v, 0.0f), 1.0f);
        out[((size_t)img << 20) + y * W + x] = v;
    }
}

// ---------------------------------------------------------------- launch
extern "C" void kernel_launch(void* const* d_in, const int* in_sizes, int n_in,
                              void* d_out, int out_size, void* d_ws, size_t ws_size,
                              hipStream_t stream) {
    const float* base = (const float*)d_in[0];
    float* out = (float*)d_out;

    float* gm     = (float*)d_ws;
    int*   labels = (int*)((char*)d_ws + (size_t)TOT * 4);
    int*   counts = (int*)((char*)d_ws + 2ull * (size_t)TOT * 4);
    ull*   mask   = (ull*)((char*)d_ws + 3ull * (size_t)TOT * 4);
    size_t needed = 3ull * (size_t)TOT * 4 + (size_t)NWORDS * 8;
    bool use_mask = (ws_size >= needed);

    dim3 block(256);
    dim3 gridPix(TOT / 256);
    dim3 gridWords(NWORDS / 256);
    dim3 gridTiles(NIMG * (H / TY) * (W / TX));

    gm_kernel<<<gridPix, block, 0, stream>>>(base, gm, use_mask ? mask : nullptr,
                                             labels, counts);
    if (use_mask) {
        merge_words<<<gridWords, block, 0, stream>>>(mask, labels);
        count_words<<<gridWords, block, 0, stream>>>(mask, labels, counts);
    } else {
        merge_px<<<gridPix, block, 0, stream>>>(gm, labels);
        count_px<<<gridPix, block, 0, stream>>>(gm, labels, counts);
    }
    final_kernel<<<gridTiles, block, 0, stream>>>(gm, labels, counts, out);
}

// Round 3
// 96.015 us; speedup vs baseline: 1.8903x; 1.0438x over previous
//
#include <hip/hip_runtime.h>

#define H 1024
#define W 1024
#define NPIX (H * W)
#define NIMG 12
#define TOT (NIMG * NPIX)
#define NWORDS (TOT / 64)   /* 196608 fg-mask words (64 px each) */
#define WPR 16              /* mask words per image row */
#define WPI (NPIX / 64)     /* mask words per image */

#define EXACT_DIV 0  /* 1 = bitwise-exact /9 divides; 0 = algebraic (1-ulp) */

typedef unsigned long long ull;

// Constants computed in double then demoted to float, matching Python/JAX.
__device__ __constant__ float C_HALF = (float)(0.5 * (1.0 / 1023.0));
__device__ __constant__ float C_FOUR = (float)(4.0 * (1.0 / 1023.0));
__device__ __constant__ float C_ONE  = (float)(1.0 * (1.0 / 1023.0));
#define SCALE 255.75f  /* 1023/4, exact */

// ------------------------------------------------------------------ gm pass
__global__ __launch_bounds__(256) void gm_kernel(const float* __restrict__ in,
                                                 float* __restrict__ gm,
                                                 ull* __restrict__ mask,
                                                 int* __restrict__ labels,
                                                 int* __restrict__ counts) {
    int idx = blockIdx.x * blockDim.x + threadIdx.x;
    int p   = idx & (NPIX - 1);
    int y = p >> 10, x = p & 1023;
    const float* im = in + ((size_t)(idx >> 20) << 20);

    float xm1 = (x >= 1)     ? im[p - 1] : 0.0f;
    float xp1 = (x < W - 1)  ? im[p + 1] : 0.0f;
    float xm2 = (x >= 2)     ? im[p - 2] : 0.0f;
    float xp2 = (x < W - 2)  ? im[p + 2] : 0.0f;
    float xm3 = (x >= 3)     ? im[p - 3] : 0.0f;
    float xp3 = (x < W - 3)  ? im[p + 3] : 0.0f;
    float g1 = xm1 - xp1;
    float g2 = xm2 - xp2;
    float g3 = xm3 - xp3;
    float gmer = (g1 + g2 + g3) / 3.0f;
    float a = fabsf(g1);
    bool keep = (fabsf(gmer - g1) <= C_HALF) & (a <= C_FOUR) & (a > C_ONE);
    float gx = keep ? a : 0.0f;

    float ym1 = (y >= 1)    ? im[p - W]     : 0.0f;
    float yp1 = (y < H - 1) ? im[p + W]     : 0.0f;
    float ym2 = (y >= 2)    ? im[p - 2 * W] : 0.0f;
    float yp2 = (y < H - 2) ? im[p + 2 * W] : 0.0f;
    float ym3 = (y >= 3)    ? im[p - 3 * W] : 0.0f;
    float yp3 = (y < H - 3) ? im[p + 3 * W] : 0.0f;
    g1 = ym1 - yp1;
    g2 = ym2 - yp2;
    g3 = ym3 - yp3;
    gmer = (g1 + g2 + g3) / 3.0f;
    a = fabsf(g1);
    keep = (fabsf(gmer - g1) <= C_HALF) & (a <= C_FOUR) & (a > C_ONE);
    float gy = keep ? a : 0.0f;

    float gmv = fmaxf(gx, gy) * SCALE;
    gm[idx] = gmv;

    bool fg = gmv > 1.0f;
    if (mask) {
        ull m = __ballot(fg);
        if ((threadIdx.x & 63) == 0) mask[idx >> 6] = m;
    }
    if (fg) {
        labels[idx] = p;   // per-image pixel index
        counts[idx] = 0;   // roots are fg pixels; zero before count pass
    }
}

// ------------------------------------------------------------- union-find
__device__ __forceinline__ int find_root(int* L, int a) {
    int l = L[a];
    while (l != a) { a = l; l = L[a]; }
    return a;
}

__device__ __forceinline__ void unite(int* L, int a, int b) {
    while (true) {
        a = find_root(L, a);
        b = find_root(L, b);
        if (a == b) return;
        if (a > b) { int t = a; a = b; b = t; }
        int old = atomicMin(&L[b], a);
        if (old == b) return;
        b = old;
    }
}

// ------------------------------------------- word-based (sparse) CCL kernels
__global__ __launch_bounds__(256) void merge_words(const ull* __restrict__ mask,
                                                   int* __restrict__ labels) {
    int w = blockIdx.x * blockDim.x + threadIdx.x;
    ull m = mask[w];
    if (!m) return;
    int img = w >> 14;
    int wp  = w & (WPI - 1);
    int row = wp >> 4, colw = wp & 15;
    int* L = labels + ((size_t)img << 20);
    bool hasS = row < H - 1, hasE = colw < 15, hasW = colw > 0;
    ull mS   = hasS ? mask[w + WPR] : 0ull;
    ull mE1  = hasE ? mask[w + 1] : 0ull;
    ull mSWw = (hasS && hasW) ? mask[w + WPR - 1] : 0ull;
    ull mSEw = (hasS && hasE) ? mask[w + WPR + 1] : 0ull;
    ull fgE  = (m >> 1) | (mE1 << 63);
    ull fgS  = mS;
    ull fgSW = (mS << 1) | (mSWw >> 63);
    ull fgSE = (mS >> 1) | (mSEw << 63);
    int pbase = wp << 6;
    ull t = m;
    while (t) {
        int b = __builtin_ctzll(t);
        t &= t - 1;
        int p = pbase + b;
        ull bit = 1ull << b;
        if (fgE & bit)  unite(L, p, p + 1);
        if (fgSW & bit) unite(L, p, p + W - 1);
        if (fgS & bit)  unite(L, p, p + W);
        if (fgSE & bit) unite(L, p, p + W + 1);
    }
}

__global__ __launch_bounds__(256) void count_words(const ull* __restrict__ mask,
                                                   int* __restrict__ labels,
                                                   int* __restrict__ counts) {
    int w = blockIdx.x * blockDim.x + threadIdx.x;
    ull m = mask[w];
    if (!m) return;
    int img = w >> 14;
    int wp  = w & (WPI - 1);
    int row = wp >> 4, colw = wp & 15;
    int* L = labels + ((size_t)img << 20);
    int* C = counts + ((size_t)img << 20);
    ull mN  = (row > 0)     ? mask[w - WPR] : 0ull;
    ull mS  = (row < H - 1) ? mask[w + WPR] : 0ull;
    ull mE1 = (colw < 15)   ? mask[w + 1]   : 0ull;
    ull mWw = (colw > 0)    ? mask[w - 1]   : 0ull;
    ull fgE = (m >> 1) | (mE1 << 63);
    ull fgW = (m << 1) | (mWw >> 63);
    ull boundary = m & ~(mN & mS & fgE & fgW);
    int pbase = wp << 6;
    while (boundary) {
        int b = __builtin_ctzll(boundary);
        boundary &= boundary - 1;
        int p = pbase + b;
        int r = find_root(L, p);
        L[p] = r;                 // flatten boundary pixels (read by final)
        atomicAdd(&C[r], 1);
    }
}

// ------------------------------------- per-pixel fallback CCL (ws too small)
__global__ __launch_bounds__(256) void merge_px(const float* __restrict__ gm,
                                                int* __restrict__ labels) {
    int idx = blockIdx.x * blockDim.x + threadIdx.x;
    int p = idx & (NPIX - 1);
    const float* g = gm + ((size_t)(idx >> 20) << 20);
    if (!(g[p] > 1.0f)) return;
    int y = p >> 10, x = p & 1023;
    int* L = labels + ((size_t)(idx >> 20) << 20);
    if (x < W - 1 && g[p + 1] > 1.0f) unite(L, p, p + 1);
    if (y < H - 1) {
        if (x >= 1    && g[p + W - 1] > 1.0f) unite(L, p, p + W - 1);
        if (             g[p + W]     > 1.0f) unite(L, p, p + W);
        if (x < W - 1 && g[p + W + 1] > 1.0f) unite(L, p, p + W + 1);
    }
}

__global__ __launch_bounds__(256) void count_px(const float* __restrict__ gm,
                                                int* __restrict__ labels,
                                                int* __restrict__ counts) {
    int idx = blockIdx.x * blockDim.x + threadIdx.x;
    int p = idx & (NPIX - 1);
    const float* g = gm + ((size_t)(idx >> 20) << 20);
    if (!(g[p] > 1.0f)) return;
    int y = p >> 10, x = p & 1023;
    bool interior = (y >= 1 && g[p - W] > 1.0f) && (y < H - 1 && g[p + W] > 1.0f) &&
                    (x >= 1 && g[p - 1] > 1.0f) && (x < W - 1 && g[p + 1] > 1.0f);
    if (!interior) {
        int* L = labels + ((size_t)(idx >> 20) << 20);
        int r = find_root(L, p);
        L[p] = r;
        atomicAdd(&counts[((size_t)(idx >> 20) << 20) + r], 1);
    }
}

// ---------------------------------------------------------------- final
#define TX 64
#define TY 32
#define GW (TX + 4)  /* 68 */
#define GH (TY + 4)  /* 36 */
#define PW (TX + 2)  /* 66 */
#define PH (TY + 2)  /* 34 */

__global__ __launch_bounds__(256) void final_kernel(const float* __restrict__ gm,
                                                    const int* __restrict__ labels,
                                                    const int* __restrict__ counts,
                                                    float* __restrict__ out) {
    __shared__ float gs[GH * GW];
    __shared__ float pxx[PH * PW];
    __shared__ float pyy[PH * PW];
    __shared__ float pxy[PH * PW];

    int bid = blockIdx.x;
    int img = bid >> 9;           // 512 tiles per image (16 x * 32 y)
    int rem = bid & 511;
    int ty0 = (rem >> 4) * TY;
    int tx0 = (rem & 15) * TX;
    const float* g = gm + ((size_t)img << 20);
    int t = threadIdx.x;

    // stage gm tile + halo 2 (zero-filled outside image)
    for (int i = t; i < GH * GW; i += 256) {
        int ly = i / GW, lx = i - ly * GW;
        int gr = ty0 - 2 + ly, gc = tx0 - 2 + lx;
        float v = 0.0f;
        if ((unsigned)gr < H && (unsigned)gc < W) v = g[gr * W + gc];
        gs[i] = v;
    }
    __syncthreads();

    // gradient products, halo 1, with reflect-at-image-edge baked into the
    // halo slots (bitwise-equal to reflecting the product values).
    for (int i = t; i < PH * PW; i += 256) {
        int ly = i / PW, lx = i - ly * PW;
        int r = ty0 - 1 + ly;
        int c = tx0 - 1 + lx;
        if (r < 0) r = 1; else if (r >= H) r = H - 2;   // reflect
        if (c < 0) c = 1; else if (c >= W) c = W - 2;   // reflect
        int lr = r - (ty0 - 2);
        int lc = c - (tx0 - 2);
        float gxv = gs[lr * GW + lc - 1]   - gs[lr * GW + lc + 1];
        float gyv = gs[(lr - 1) * GW + lc] - gs[(lr + 1) * GW + lc];
        pxx[i] = gxv * gxv;
        pyy[i] = gyv * gyv;
        pxy[i] = gxv * gyv;
    }
    __syncthreads();

    int ox = t & 63;
    int rg = t >> 6;
    int base = rg * 8;            // first output row of this thread's strip
    int x = tx0 + ox;

    // sliding 3x3 window over product rows (stored rows oy..oy+2)
    float wxx[2][3], wyy[2][3], wxy[2][3];
    #pragma unroll
    for (int rsel = 0; rsel < 2; ++rsel) {
        #pragma unroll
        for (int j = 0; j < 3; ++j) {
            int o = (base + rsel) * PW + ox + j;
            wxx[rsel][j] = pxx[o];
            wyy[rsel][j] = pyy[o];
            wxy[rsel][j] = pxy[o];
        }
    }

    #pragma unroll
    for (int i = 0; i < 8; ++i) {
        int oy = base + i;
        int y = ty0 + oy;
        float nxx[3], nyy[3], nxy[3];
        #pragma unroll
        for (int j = 0; j < 3; ++j) {
            int o = (oy + 2) * PW + ox + j;
            nxx[j] = pxx[o];
            nyy[j] = pyy[o];
            nxy[j] = pxy[o];
        }
        // exact row-major accumulation order (matches reference _blur3)
        float sxx = ((((((wxx[0][0] + wxx[0][1]) + wxx[0][2]) + wxx[1][0]) +
                       wxx[1][1]) + wxx[1][2]) + nxx[0]) + nxx[1] + nxx[2];
        float syy = ((((((wyy[0][0] + wyy[0][1]) + wyy[0][2]) + wyy[1][0]) +
                       wyy[1][1]) + wyy[1][2]) + nyy[0]) + nyy[1] + nyy[2];
        float sxy = ((((((wxy[0][0] + wxy[0][1]) + wxy[0][2]) + wxy[1][0]) +
                       wxy[1][1]) + wxy[1][2]) + nxy[0]) + nxy[1] + nxy[2];
        // shift window
        #pragma unroll
        for (int j = 0; j < 3; ++j) {
            wxx[0][j] = wxx[1][j]; wxx[1][j] = nxx[j];
            wyy[0][j] = wyy[1][j]; wyy[1][j] = nyy[j];
            wxy[0][j] = wxy[1][j]; wxy[1][j] = nxy[j];
        }

#if EXACT_DIV
        sxx /= 9.0f; syy /= 9.0f; sxy /= 9.0f;
        float d = sxx - syy;
        float tmp = sqrtf(d * d + 4.0f * sxy * sxy);
        float dmv = tmp / (sxx + syy + 1e-16f);
#else
        // dm is scale-invariant: tmp/9 over (sxx+syy)/9 + 1e-16 ==
        // tmp over (sxx+syy) + 9e-16 (1-ulp perturbation, no discrete use)
        float d = sxx - syy;
        float tmp = sqrtf(d * d + 4.0f * sxy * sxy);
        float dmv = tmp / (sxx + syy + 9e-16f);
#endif

        float gc_ = gs[(oy + 2) * GW + ox + 2];
        float lm = 0.0f;
        if (gc_ > 1.0f) {
            bool interior = (gs[(oy + 1) * GW + ox + 2] > 1.0f) &
                            (gs[(oy + 3) * GW + ox + 2] > 1.0f) &
                            (gs[(oy + 2) * GW + ox + 1] > 1.0f) &
                            (gs[(oy + 2) * GW + ox + 3] > 1.0f);
            if (!interior) {
                int p = y * W + x;
                int c = counts[((size_t)img << 20) + labels[((size_t)img << 20) + p]];
                if (c > 21) lm = (float)c;
            }
        }
        float v = gc_ * dmv * lm;
        v = fminf(fmaxf(v, 0.0f), 1.0f);
        out[((size_t)img << 20) + y * W + x] = v;
    }
}

// ---------------------------------------------------------------- launch
extern "C" void kernel_launch(void* const* d_in, const int* in_sizes, int n_in,
                              void* d_out, int out_size, void* d_ws, size_t ws_size,
                              hipStream_t stream) {
    const float* base = (const float*)d_in[0];
    float* out = (float*)d_out;

    float* gm     = (float*)d_ws;
    int*   labels = (int*)((char*)d_ws + (size_t)TOT * 4);
    int*   counts = (int*)((char*)d_ws + 2ull * (size_t)TOT * 4);
    ull*   mask   = (ull*)((char*)d_ws + 3ull * (size_t)TOT * 4);
    size_t needed = 3ull * (size_t)TOT * 4 + (size_t)NWORDS * 8;
    bool use_mask = (ws_size >= needed);

    dim3 block(256);
    dim3 gridPix(TOT / 256);
    dim3 gridWords(NWORDS / 256);
    dim3 gridTiles(NIMG * (H / TY) * (W / TX));

    gm_kernel<<<gridPix, block, 0, stream>>>(base, gm, use_mask ? mask : nullptr,
                                             labels, counts);
    if (use_mask) {
        merge_words<<<gridWords, block, 0, stream>>>(mask, labels);
        count_words<<<gridWords, block, 0, stream>>>(mask, labels, counts);
    } else {
        merge_px<<<gridPix, block, 0, stream>>>(gm, labels);
        count_px<<<gridPix, block, 0, stream>>>(gm, labels, counts);
    }
    final_kernel<<<gridTiles, block, 0, stream>>>(gm, labels, counts, out);
}

// Round 4
// 93.076 us; speedup vs baseline: 1.9500x; 1.0316x over previous
//
#include <hip/hip_runtime.h>

#define H 1024
#define W 1024
#define NPIX (H * W)
#define NIMG 12
#define TOT (NIMG * NPIX)
#define NWORDS (TOT / 64)   /* 196608 fg-mask words (64 px each) */
#define WPR 16              /* mask words per image row */
#define WPI (NPIX / 64)     /* mask words per image */

typedef unsigned long long ull;

// Constants computed in double then demoted to float, matching Python/JAX.
__device__ __constant__ float C_HALF = (float)(0.5 * (1.0 / 1023.0));
__device__ __constant__ float C_FOUR = (float)(4.0 * (1.0 / 1023.0));
__device__ __constant__ float C_ONE  = (float)(1.0 * (1.0 / 1023.0));
#define SCALE 255.75f  /* 1023/4, exact */

// --------------------------------------------------------------- gm (dense)
// 4 pixels per thread, fully vectorized loads; gm never stored.
__global__ __launch_bounds__(256) void gm_kernel(const float* __restrict__ in,
                                                 float* __restrict__ out,
                                                 ull* __restrict__ mask,
                                                 int* __restrict__ labels,
                                                 int* __restrict__ counts) {
    int gid = blockIdx.x * blockDim.x + threadIdx.x;
    int p0g = gid << 2;                 // global pixel index of lane's 1st px
    int img = p0g >> 20;
    int p0  = p0g & (NPIX - 1);
    int y   = p0 >> 10;
    int x0  = p0 & 1023;
    const float* im = in + ((size_t)img << 20);

    const float4 z4 = make_float4(0.f, 0.f, 0.f, 0.f);
    // x-window: 12 floats covering columns x0-4 .. x0+7
    float4 A = (x0 >= 4)   ? *(const float4*)(im + p0 - 4) : z4;
    float4 B =               *(const float4*)(im + p0);
    float4 C = (x0 < 1020) ? *(const float4*)(im + p0 + 4) : z4;
    float wnd[12] = {A.x, A.y, A.z, A.w, B.x, B.y, B.z, B.w, C.x, C.y, C.z, C.w};
    // y-rows at this x0
    float4 r_m[3], r_p[3];
    #pragma unroll
    for (int j = 1; j <= 3; ++j) {
        r_m[j - 1] = (y >= j)     ? *(const float4*)(im + p0 - j * W) : z4;
        r_p[j - 1] = (y < H - j)  ? *(const float4*)(im + p0 + j * W) : z4;
    }
    const float* rm1 = (const float*)&r_m[0];
    const float* rm2 = (const float*)&r_m[1];
    const float* rm3 = (const float*)&r_m[2];
    const float* rp1 = (const float*)&r_p[0];
    const float* rp2 = (const float*)&r_p[1];
    const float* rp3 = (const float*)&r_p[2];

    unsigned nib = 0;
    #pragma unroll
    for (int k = 0; k < 4; ++k) {
        // axis=1 (x)
        float g1 = wnd[k + 3] - wnd[k + 5];
        float g2 = wnd[k + 2] - wnd[k + 6];
        float g3 = wnd[k + 1] - wnd[k + 7];
        float gmer = (g1 + g2 + g3) / 3.0f;
        float a = fabsf(g1);
        bool keep = (fabsf(gmer - g1) <= C_HALF) & (a <= C_FOUR) & (a > C_ONE);
        float gx = keep ? a : 0.0f;
        // axis=0 (y)
        g1 = rm1[k] - rp1[k];
        g2 = rm2[k] - rp2[k];
        g3 = rm3[k] - rp3[k];
        gmer = (g1 + g2 + g3) / 3.0f;
        a = fabsf(g1);
        keep = (fabsf(gmer - g1) <= C_HALF) & (a <= C_FOUR) & (a > C_ONE);
        float gy = keep ? a : 0.0f;

        float gmv = fmaxf(gx, gy) * SCALE;
        bool fg = gmv > 1.0f;
        if (fg) {
            int p = p0 + k;
            labels[((size_t)img << 20) + p] = p;
            counts[((size_t)img << 20) + p] = 0;
        }
        nib |= (unsigned)fg << k;
    }

    // zero the output (sparse_final overwrites the few nonzero pixels later)
    *(float4*)(out + p0g) = z4;

    // assemble 64-px mask words: 16 lanes x 4 bits, butterfly OR
    int lane = threadIdx.x & 63;
    ull v = (ull)nib << ((lane & 15) << 2);
    v |= __shfl_xor((long long)v, 1);
    v |= __shfl_xor((long long)v, 2);
    v |= __shfl_xor((long long)v, 4);
    v |= __shfl_xor((long long)v, 8);
    if ((lane & 15) == 0) mask[p0g >> 6] = v;
}

// ------------------------------------------------------------- union-find
__device__ __forceinline__ int find_root(int* L, int a) {
    int l = L[a];
    while (l != a) { a = l; l = L[a]; }
    return a;
}

__device__ __forceinline__ void unite(int* L, int a, int b) {
    while (true) {
        a = find_root(L, a);
        b = find_root(L, b);
        if (a == b) return;
        if (a > b) { int t = a; a = b; b = t; }
        int old = atomicMin(&L[b], a);
        if (old == b) return;
        b = old;
    }
}

// ------------------------------------------- word-based (sparse) CCL kernels
__global__ __launch_bounds__(256) void merge_words(const ull* __restrict__ mask,
                                                   int* __restrict__ labels) {
    int w = blockIdx.x * blockDim.x + threadIdx.x;
    ull m = mask[w];
    if (!m) return;
    int img = w >> 14;
    int wp  = w & (WPI - 1);
    int row = wp >> 4, colw = wp & 15;
    int* L = labels + ((size_t)img << 20);
    bool hasS = row < H - 1, hasE = colw < 15, hasW = colw > 0;
    ull mS   = hasS ? mask[w + WPR] : 0ull;
    ull mE1  = hasE ? mask[w + 1] : 0ull;
    ull mSWw = (hasS && hasW) ? mask[w + WPR - 1] : 0ull;
    ull mSEw = (hasS && hasE) ? mask[w + WPR + 1] : 0ull;
    ull fgE  = (m >> 1) | (mE1 << 63);
    ull fgS  = mS;
    ull fgSW = (mS << 1) | (mSWw >> 63);
    ull fgSE = (mS >> 1) | (mSEw << 63);
    int pbase = wp << 6;
    ull t = m;
    while (t) {
        int b = __builtin_ctzll(t);
        t &= t - 1;
        int p = pbase + b;
        ull bit = 1ull << b;
        if (fgE & bit)  unite(L, p, p + 1);
        if (fgSW & bit) unite(L, p, p + W - 1);
        if (fgS & bit)  unite(L, p, p + W);
        if (fgSE & bit) unite(L, p, p + W + 1);
    }
}

__global__ __launch_bounds__(256) void count_words(const ull* __restrict__ mask,
                                                   int* __restrict__ labels,
                                                   int* __restrict__ counts) {
    int w = blockIdx.x * blockDim.x + threadIdx.x;
    ull m = mask[w];
    if (!m) return;
    int img = w >> 14;
    int wp  = w & (WPI - 1);
    int row = wp >> 4, colw = wp & 15;
    int* L = labels + ((size_t)img << 20);
    int* C = counts + ((size_t)img << 20);
    ull mN  = (row > 0)     ? mask[w - WPR] : 0ull;
    ull mS  = (row < H - 1) ? mask[w + WPR] : 0ull;
    ull mE1 = (colw < 15)   ? mask[w + 1]   : 0ull;
    ull mWw = (colw > 0)    ? mask[w - 1]   : 0ull;
    ull fgE = (m >> 1) | (mE1 << 63);
    ull fgW = (m << 1) | (mWw >> 63);
    ull boundary = m & ~(mN & mS & fgE & fgW);
    int pbase = wp << 6;
    while (boundary) {
        int b = __builtin_ctzll(boundary);
        boundary &= boundary - 1;
        int p = pbase + b;
        int r = find_root(L, p);
        L[p] = r;                 // flatten boundary pixels (read by final)
        atomicAdd(&C[r], 1);
    }
}

// --------------------------------------------------- sparse final (dm eval)
// Recompute gm bitwise-identically to gm_kernel, scalar, at (y,x); zero-fill
// shifts at image edges (matches reference _shift fill=0).
__device__ float gm_eval(const float* __restrict__ im, int y, int x) {
    int p = y * W + x;
    float xm1 = (x >= 1)     ? im[p - 1] : 0.0f;
    float xp1 = (x < W - 1)  ? im[p + 1] : 0.0f;
    float xm2 = (x >= 2)     ? im[p - 2] : 0.0f;
    float xp2 = (x < W - 2)  ? im[p + 2] : 0.0f;
    float xm3 = (x >= 3)     ? im[p - 3] : 0.0f;
    float xp3 = (x < W - 3)  ? im[p + 3] : 0.0f;
    float g1 = xm1 - xp1;
    float g2 = xm2 - xp2;
    float g3 = xm3 - xp3;
    float gmer = (g1 + g2 + g3) / 3.0f;
    float a = fabsf(g1);
    bool keep = (fabsf(gmer - g1) <= C_HALF) & (a <= C_FOUR) & (a > C_ONE);
    float gx = keep ? a : 0.0f;

    float ym1 = (y >= 1)    ? im[p - W]     : 0.0f;
    float yp1 = (y < H - 1) ? im[p + W]     : 0.0f;
    float ym2 = (y >= 2)    ? im[p - 2 * W] : 0.0f;
    float yp2 = (y < H - 2) ? im[p + 2 * W] : 0.0f;
    float ym3 = (y >= 3)    ? im[p - 3 * W] : 0.0f;
    float yp3 = (y < H - 3) ? im[p + 3 * W] : 0.0f;
    g1 = ym1 - yp1;
    g2 = ym2 - yp2;
    g3 = ym3 - yp3;
    gmer = (g1 + g2 + g3) / 3.0f;
    a = fabsf(g1);
    keep = (fabsf(gmer - g1) <= C_HALF) & (a <= C_FOUR) & (a > C_ONE);
    float gy = keep ? a : 0.0f;

    return fmaxf(gx, gy) * SCALE;
}

__device__ __forceinline__ float gmz(const float* __restrict__ im, int y, int x) {
    if ((unsigned)y >= H || (unsigned)x >= W) return 0.0f;  // zero fill
    return gm_eval(im, y, x);
}

__global__ __launch_bounds__(256) void sparse_final(const float* __restrict__ in,
                                                    const ull* __restrict__ mask,
                                                    const int* __restrict__ labels,
                                                    const int* __restrict__ counts,
                                                    float* __restrict__ out) {
    #pragma clang fp contract(off)
    int w = blockIdx.x * blockDim.x + threadIdx.x;
    ull m = mask[w];
    if (!m) return;
    int img = w >> 14;
    int wp  = w & (WPI - 1);
    int row = wp >> 4, colw = wp & 15;
    const float* im = in + ((size_t)img << 20);
    const int* L = labels + ((size_t)img << 20);
    const int* C = counts + ((size_t)img << 20);
    ull mN  = (row > 0)     ? mask[w - WPR] : 0ull;
    ull mS  = (row < H - 1) ? mask[w + WPR] : 0ull;
    ull mE1 = (colw < 15)   ? mask[w + 1]   : 0ull;
    ull mWw = (colw > 0)    ? mask[w - 1]   : 0ull;
    ull fgE = (m >> 1) | (mE1 << 63);
    ull fgW = (m << 1) | (mWw >> 63);
    ull boundary = m & ~(mN & mS & fgE & fgW);
    int pbase = wp << 6;
    while (boundary) {
        int b = __builtin_ctzll(boundary);
        boundary &= boundary - 1;
        int p = pbase + b;
        int c = C[L[p]];
        if (c <= 21) continue;          // lm == 0 -> out stays 0
        int y = p >> 10, x = p & 1023;

        // directmask at (y,x): 3x3 reflect blur of gradient products
        float sxx = 0.0f, syy = 0.0f, sxy = 0.0f;
        #pragma unroll
        for (int di = -1; di <= 1; ++di) {
            int r = y + di;
            if (r < 0) r = -r;
            if (r >= H) r = 2 * H - 2 - r;
            #pragma unroll
            for (int dj = -1; dj <= 1; ++dj) {
                int cc = x + dj;
                if (cc < 0) cc = -cc;
                if (cc >= W) cc = 2 * W - 2 - cc;
                float gxv = gmz(im, r, cc - 1) - gmz(im, r, cc + 1);
                float gyv = gmz(im, r - 1, cc) - gmz(im, r + 1, cc);
                float txx = gxv * gxv;
                float tyy = gyv * gyv;
                float txy = gxv * gyv;
                sxx = sxx + txx;
                syy = syy + tyy;
                sxy = sxy + txy;
            }
        }
        sxx /= 9.0f; syy /= 9.0f; sxy /= 9.0f;
        float d = sxx - syy;
        float tmp = sqrtf(d * d + 4.0f * (sxy * sxy));
        float dmv = tmp / (sxx + syy + 1e-16f);

        float gc_ = gm_eval(im, y, x);
        float v = gc_ * dmv * (float)c;
        v = fminf(fmaxf(v, 0.0f), 1.0f);
        out[((size_t)img << 20) + p] = v;
    }
}

// ---------------------------------------------------------------- launch
extern "C" void kernel_launch(void* const* d_in, const int* in_sizes, int n_in,
                              void* d_out, int out_size, void* d_ws, size_t ws_size,
                              hipStream_t stream) {
    const float* base = (const float*)d_in[0];
    float* out = (float*)d_out;

    int* labels = (int*)d_ws;
    int* counts = (int*)((char*)d_ws + (size_t)TOT * 4);
    ull* mask   = (ull*)((char*)d_ws + 2ull * (size_t)TOT * 4);

    dim3 block(256);
    dim3 gridQ(TOT / 4 / 256);
    dim3 gridWords(NWORDS / 256);

    gm_kernel<<<gridQ, block, 0, stream>>>(base, out, mask, labels, counts);
    merge_words<<<gridWords, block, 0, stream>>>(mask, labels);
    count_words<<<gridWords, block, 0, stream>>>(mask, labels, counts);
    sparse_final<<<gridWords, block, 0, stream>>>(base, mask, labels, counts, out);
}

// Round 5
// 39.550 us; speedup vs baseline: 4.5890x; 2.3534x over previous
//
#include <hip/hip_runtime.h>

#define H 1024
#define W 1024
#define NPIX (H * W)
#define NIMG 12
#define TOT (NIMG * NPIX)
#define NWORDS (TOT / 64)   /* 196608 fg-mask words (64 px each) */
#define WPR 16              /* mask words per image row */
#define WPI (NPIX / 64)     /* mask words per image */

#define RSTRIP 8                      /* rows per block strip */
#define NBLK (NIMG * (H / RSTRIP))    /* 1536 gm blocks */

typedef unsigned long long ull;

// Constants computed in double then demoted to float, matching Python/JAX.
__device__ __constant__ float C_HALF = (float)(0.5 * (1.0 / 1023.0));
__device__ __constant__ float C_FOUR = (float)(4.0 * (1.0 / 1023.0));
__device__ __constant__ float C_ONE  = (float)(1.0 * (1.0 / 1023.0));
#define SCALE 255.75f  /* 1023/4, exact */

// static component select (folds to a register pick under full unroll)
#define COMP(v, k) ((k) == 0 ? (v).x : (k) == 1 ? (v).y : (k) == 2 ? (v).z : (v).w)

// --------------------------------------------------------------- gm (dense)
// One float4-column x 8-row strip per thread; 7-row sliding register window.
__global__ __launch_bounds__(256) void gm_kernel(const float* __restrict__ in,
                                                 float* __restrict__ out,
                                                 ull* __restrict__ mask,
                                                 int* __restrict__ labels,
                                                 int* __restrict__ counts) {
    int bid = blockIdx.x;
    // XCD-chunked swizzle: contiguous strips stay on one XCD's L2 (1536%8==0)
    int wblk = (bid & 7) * (NBLK / 8) + (bid >> 3);
    int img   = wblk >> 7;            // 128 strips per image
    int strip = wblk & 127;
    int y0 = strip * RSTRIP;
    int t  = threadIdx.x;             // float4-column, 256 per row
    int x0 = t << 2;
    const float* im = in + ((size_t)img << 20);
    float* ob = out + ((size_t)img << 20);
    int lane = t & 63;

    const float4 z4 = make_float4(0.f, 0.f, 0.f, 0.f);
    float4 win[7];                    // rows y-3 .. y+3 of this column
    #pragma unroll
    for (int j = 0; j < 6; ++j) {
        int yy = y0 - 3 + j;
        win[j] = (yy >= 0) ? *(const float4*)(im + yy * W + x0) : z4;
    }

    #pragma unroll
    for (int i = 0; i < RSTRIP; ++i) {
        int y = y0 + i;
        int yl = y + 3;
        win[6] = (yl < H) ? *(const float4*)(im + yl * W + x0) : z4;
        float4 A = (x0 >= 4)    ? *(const float4*)(im + y * W + x0 - 4) : z4;
        float4 B = win[3];
        float4 Cv = (x0 < 1020) ? *(const float4*)(im + y * W + x0 + 4) : z4;
        // wnd[i] = column x0-4+i  (static indices only)
        float wnd[12] = {A.x, A.y, A.z, A.w, B.x, B.y, B.z, B.w,
                         Cv.x, Cv.y, Cv.z, Cv.w};

        unsigned nib = 0;
        #pragma unroll
        for (int k = 0; k < 4; ++k) {
            // axis=1 (x): d(k') = col(x-k') - col(x+k'), zero fill
            float g1 = wnd[k + 3] - wnd[k + 5];
            float g2 = wnd[k + 2] - wnd[k + 6];
            float g3 = wnd[k + 1] - wnd[k + 7];
            float gmer = (g1 + g2 + g3) / 3.0f;
            float a = fabsf(g1);
            bool keep = (fabsf(gmer - g1) <= C_HALF) & (a <= C_FOUR) & (a > C_ONE);
            float gx = keep ? a : 0.0f;
            // axis=0 (y)
            g1 = COMP(win[2], k) - COMP(win[4], k);
            g2 = COMP(win[1], k) - COMP(win[5], k);
            g3 = COMP(win[0], k) - COMP(win[6], k);
            gmer = (g1 + g2 + g3) / 3.0f;
            a = fabsf(g1);
            keep = (fabsf(gmer - g1) <= C_HALF) & (a <= C_FOUR) & (a > C_ONE);
            float gy = keep ? a : 0.0f;

            float gmv = fmaxf(gx, gy) * SCALE;
            bool fg = gmv > 1.0f;
            if (fg) {
                int p = y * W + x0 + k;
                labels[((size_t)img << 20) + p] = p;
                counts[((size_t)img << 20) + p] = 0;
            }
            nib |= (unsigned)fg << k;
        }

        // zero output row segment (sparse_final rewrites the few nonzeros)
        *(float4*)(ob + y * W + x0) = z4;

        // 64-px mask words: 16 lanes x 4 bits, butterfly OR within 16-lane grp
        ull v = (ull)nib << ((lane & 15) << 2);
        v |= __shfl_xor((long long)v, 1);
        v |= __shfl_xor((long long)v, 2);
        v |= __shfl_xor((long long)v, 4);
        v |= __shfl_xor((long long)v, 8);
        if ((lane & 15) == 0) {
            int p0g = (img << 14) + (y << 4) + (x0 >> 6);  // word index
            mask[p0g] = v;
        }

        // slide window
        #pragma unroll
        for (int j = 0; j < 6; ++j) win[j] = win[j + 1];
    }
}

// ------------------------------------------------------------- union-find
__device__ __forceinline__ int find_root(int* L, int a) {
    int l = L[a];
    while (l != a) { a = l; l = L[a]; }
    return a;
}

__device__ __forceinline__ void unite(int* L, int a, int b) {
    while (true) {
        a = find_root(L, a);
        b = find_root(L, b);
        if (a == b) return;
        if (a > b) { int t = a; a = b; b = t; }
        int old = atomicMin(&L[b], a);
        if (old == b) return;
        b = old;
    }
}

// ------------------------------------------- word-based (sparse) CCL kernels
__global__ __launch_bounds__(256) void merge_words(const ull* __restrict__ mask,
                                                   int* __restrict__ labels) {
    int w = blockIdx.x * blockDim.x + threadIdx.x;
    ull m = mask[w];
    if (!m) return;
    int img = w >> 14;
    int wp  = w & (WPI - 1);
    int row = wp >> 4, colw = wp & 15;
    int* L = labels + ((size_t)img << 20);
    bool hasS = row < H - 1, hasE = colw < 15, hasW = colw > 0;
    ull mS   = hasS ? mask[w + WPR] : 0ull;
    ull mE1  = hasE ? mask[w + 1] : 0ull;
    ull mSWw = (hasS && hasW) ? mask[w + WPR - 1] : 0ull;
    ull mSEw = (hasS && hasE) ? mask[w + WPR + 1] : 0ull;
    ull fgE  = (m >> 1) | (mE1 << 63);
    ull fgS  = mS;
    ull fgSW = (mS << 1) | (mSWw >> 63);
    ull fgSE = (mS >> 1) | (mSEw << 63);
    int pbase = wp << 6;
    ull t = m;
    while (t) {
        int b = __builtin_ctzll(t);
        t &= t - 1;
        int p = pbase + b;
        ull bit = 1ull << b;
        if (fgE & bit)  unite(L, p, p + 1);
        if (fgSW & bit) unite(L, p, p + W - 1);
        if (fgS & bit)  unite(L, p, p + W);
        if (fgSE & bit) unite(L, p, p + W + 1);
    }
}

__global__ __launch_bounds__(256) void count_words(const ull* __restrict__ mask,
                                                   int* __restrict__ labels,
                                                   int* __restrict__ counts) {
    int w = blockIdx.x * blockDim.x + threadIdx.x;
    ull m = mask[w];
    if (!m) return;
    int img = w >> 14;
    int wp  = w & (WPI - 1);
    int row = wp >> 4, colw = wp & 15;
    int* L = labels + ((size_t)img << 20);
    int* C = counts + ((size_t)img << 20);
    ull mN  = (row > 0)     ? mask[w - WPR] : 0ull;
    ull mS  = (row < H - 1) ? mask[w + WPR] : 0ull;
    ull mE1 = (colw < 15)   ? mask[w + 1]   : 0ull;
    ull mWw = (colw > 0)    ? mask[w - 1]   : 0ull;
    ull fgE = (m >> 1) | (mE1 << 63);
    ull fgW = (m << 1) | (mWw >> 63);
    ull boundary = m & ~(mN & mS & fgE & fgW);
    int pbase = wp << 6;
    while (boundary) {
        int b = __builtin_ctzll(boundary);
        boundary &= boundary - 1;
        int p = pbase + b;
        int r = find_root(L, p);
        L[p] = r;                 // flatten boundary pixels (read by final)
        atomicAdd(&C[r], 1);
    }
}

// --------------------------------------------------- sparse final (dm eval)
// Recompute gm bitwise-identically at (y,x); zero-fill at image edges.
__device__ float gm_eval(const float* __restrict__ im, int y, int x) {
    int p = y * W + x;
    float xm1 = (x >= 1)     ? im[p - 1] : 0.0f;
    float xp1 = (x < W - 1)  ? im[p + 1] : 0.0f;
    float xm2 = (x >= 2)     ? im[p - 2] : 0.0f;
    float xp2 = (x < W - 2)  ? im[p + 2] : 0.0f;
    float xm3 = (x >= 3)     ? im[p - 3] : 0.0f;
    float xp3 = (x < W - 3)  ? im[p + 3] : 0.0f;
    float g1 = xm1 - xp1;
    float g2 = xm2 - xp2;
    float g3 = xm3 - xp3;
    float gmer = (g1 + g2 + g3) / 3.0f;
    float a = fabsf(g1);
    bool keep = (fabsf(gmer - g1) <= C_HALF) & (a <= C_FOUR) & (a > C_ONE);
    float gx = keep ? a : 0.0f;

    float ym1 = (y >= 1)    ? im[p - W]     : 0.0f;
    float yp1 = (y < H - 1) ? im[p + W]     : 0.0f;
    float ym2 = (y >= 2)    ? im[p - 2 * W] : 0.0f;
    float yp2 = (y < H - 2) ? im[p + 2 * W] : 0.0f;
    float ym3 = (y >= 3)    ? im[p - 3 * W] : 0.0f;
    float yp3 = (y < H - 3) ? im[p + 3 * W] : 0.0f;
    g1 = ym1 - yp1;
    g2 = ym2 - yp2;
    g3 = ym3 - yp3;
    gmer = (g1 + g2 + g3) / 3.0f;
    a = fabsf(g1);
    keep = (fabsf(gmer - g1) <= C_HALF) & (a <= C_FOUR) & (a > C_ONE);
    float gy = keep ? a : 0.0f;

    return fmaxf(gx, gy) * SCALE;
}

__device__ __forceinline__ float gmz(const float* __restrict__ im, int y, int x) {
    if ((unsigned)y >= H || (unsigned)x >= W) return 0.0f;  // zero fill
    return gm_eval(im, y, x);
}

__global__ __launch_bounds__(256) void sparse_final(const float* __restrict__ in,
                                                    const ull* __restrict__ mask,
                                                    const int* __restrict__ labels,
                                                    const int* __restrict__ counts,
                                                    float* __restrict__ out) {
    #pragma clang fp contract(off)
    int w = blockIdx.x * blockDim.x + threadIdx.x;
    ull m = mask[w];
    if (!m) return;
    int img = w >> 14;
    int wp  = w & (WPI - 1);
    int row = wp >> 4, colw = wp & 15;
    const float* im = in + ((size_t)img << 20);
    const int* L = labels + ((size_t)img << 20);
    const int* C = counts + ((size_t)img << 20);
    ull mN  = (row > 0)     ? mask[w - WPR] : 0ull;
    ull mS  = (row < H - 1) ? mask[w + WPR] : 0ull;
    ull mE1 = (colw < 15)   ? mask[w + 1]   : 0ull;
    ull mWw = (colw > 0)    ? mask[w - 1]   : 0ull;
    ull fgE = (m >> 1) | (mE1 << 63);
    ull fgW = (m << 1) | (mWw >> 63);
    ull boundary = m & ~(mN & mS & fgE & fgW);
    int pbase = wp << 6;
    while (boundary) {
        int b = __builtin_ctzll(boundary);
        boundary &= boundary - 1;
        int p = pbase + b;
        int c = C[L[p]];
        if (c <= 21) continue;          // lm == 0 -> out stays 0
        int y = p >> 10, x = p & 1023;

        // directmask at (y,x): 3x3 reflect blur of gradient products
        float sxx = 0.0f, syy = 0.0f, sxy = 0.0f;
        #pragma unroll
        for (int di = -1; di <= 1; ++di) {
            int r = y + di;
            if (r < 0) r = -r;
            if (r >= H) r = 2 * H - 2 - r;
            #pragma unroll
            for (int dj = -1; dj <= 1; ++dj) {
                int cc = x + dj;
                if (cc < 0) cc = -cc;
                if (cc >= W) cc = 2 * W - 2 - cc;
                float gxv = gmz(im, r, cc - 1) - gmz(im, r, cc + 1);
                float gyv = gmz(im, r - 1, cc) - gmz(im, r + 1, cc);
                float txx = gxv * gxv;
                float tyy = gyv * gyv;
                float txy = gxv * gyv;
                sxx = sxx + txx;
                syy = syy + tyy;
                sxy = sxy + txy;
            }
        }
        sxx /= 9.0f; syy /= 9.0f; sxy /= 9.0f;
        float d = sxx - syy;
        float tmp = sqrtf(d * d + 4.0f * (sxy * sxy));
        float dmv = tmp / (sxx + syy + 1e-16f);

        float gc_ = gm_eval(im, y, x);
        float v = gc_ * dmv * (float)c;
        v = fminf(fmaxf(v, 0.0f), 1.0f);
        out[((size_t)img << 20) + p] = v;
    }
}

// ---------------------------------------------------------------- launch
extern "C" void kernel_launch(void* const* d_in, const int* in_sizes, int n_in,
                              void* d_out, int out_size, void* d_ws, size_t ws_size,
                              hipStream_t stream) {
    const float* base = (const float*)d_in[0];
    float* out = (float*)d_out;

    int* labels = (int*)d_ws;
    int* counts = (int*)((char*)d_ws + (size_t)TOT * 4);
    ull* mask   = (ull*)((char*)d_ws + 2ull * (size_t)TOT * 4);

    dim3 block(256);
    dim3 gridStrips(NBLK);
    dim3 gridWords(NWORDS / 256);

    gm_kernel<<<gridStrips, block, 0, stream>>>(base, out, mask, labels, counts);
    merge_words<<<gridWords, block, 0, stream>>>(mask, labels);
    count_words<<<gridWords, block, 0, stream>>>(mask, labels, counts);
    sparse_final<<<gridWords, block, 0, stream>>>(base, mask, labels, counts, out);
}